// Round 5
// baseline (244.174 us; speedup 1.0000x reference)
//
#include <hip/hip_runtime.h>
#include <hip/hip_bf16.h>
#include <math.h>

typedef unsigned short u16;
typedef __attribute__((ext_vector_type(8))) short bf16x8;
typedef __attribute__((ext_vector_type(4))) float f32x4;
typedef __attribute__((ext_vector_type(16))) float f32x16;
typedef __attribute__((ext_vector_type(4))) unsigned int u32x4;

#define BATCH 4
#define TSEQ  2048
#define HEADS 16
#define DK    64
#define EMB   1024
#define MROWS 8192            // B*T
#define NQKV  3072
#define PHT   ((size_t)MROWS * EMB)   // 8388608 elems per Q/K/V plane

__device__ __forceinline__ u16 f2bf(float f) {
    union { float f; unsigned int i; } v;
    v.f = f;
    unsigned int x = v.i;
    return (u16)((x + 0x7FFFu + ((x >> 16) & 1u)) >> 16);  // RNE
}

// packed 2xfp32 -> 2xbf16 (RNE) in one u32
__device__ __forceinline__ unsigned int pk2bf(float a, float b) {
    float2 f2; f2.x = a; f2.y = b;
    union { __hip_bfloat162 h; unsigned int u; } cv;
    cv.h = __float22bfloat162_rn(f2);
    return cv.u;
}

// async 16B global->LDS (dest = wave-uniform base + lane*16)
__device__ __forceinline__ void gl2lds16(const u16* g, u16* l) {
    __builtin_amdgcn_global_load_lds(
        (const __attribute__((address_space(1))) unsigned int*)g,
        (__attribute__((address_space(3))) unsigned int*)l, 16, 0, 0);
}

// ---------------------------------------------------------------------------
// prep: fp32 -> bf16 convert (X); both weight transposes in ONE launch
// ---------------------------------------------------------------------------
__global__ __launch_bounds__(256) void convert_x(const float* __restrict__ X,
                                                 u16* __restrict__ Xb) {
    int i = (blockIdx.x * 256 + threadIdx.x) * 4;
    float4 v = *(const float4*)&X[i];
    ushort4 o;
    o.x = f2bf(v.x); o.y = f2bf(v.y); o.z = f2bf(v.z); o.w = f2bf(v.w);
    *(ushort4*)&Xb[i] = o;
}

// bx < 96 -> Wqkv (N=3072); else Wo (N=1024). K=1024 for both.
__global__ __launch_bounds__(256) void transpose_both(const float* __restrict__ Wqkv,
                                                      const float* __restrict__ Wo,
                                                      u16* __restrict__ Wt,
                                                      u16* __restrict__ Wot) {
    __shared__ float tile[32][33];
    const int tx = threadIdx.x & 31, ty = threadIdx.x >> 5;  // 32 x 8
    const int K = 1024;
    const float* W;
    u16* D;
    int N, bx;
    if (blockIdx.x < 96) { W = Wqkv; D = Wt; N = 3072; bx = blockIdx.x; }
    else                 { W = Wo;   D = Wot; N = 1024; bx = blockIdx.x - 96; }
    const int by = blockIdx.y;
#pragma unroll
    for (int s = 0; s < 4; s++)
        tile[ty + 8 * s][tx] = W[(size_t)(by * 32 + ty + 8 * s) * N + bx * 32 + tx];
    __syncthreads();
#pragma unroll
    for (int s = 0; s < 4; s++)
        D[(size_t)(bx * 32 + ty + 8 * s) * K + by * 32 + tx] = f2bf(tile[tx][ty + 8 * s]);
}

// ---------------------------------------------------------------------------
// MFMA GEMM core v3 (unchanged from round 3): 128x256 tile, BK=64, 8 waves,
// triple-buffered LDS + counted vmcnt + register-fragment double-buffer.
// ---------------------------------------------------------------------------
template <int KDIM>
__device__ __forceinline__ void gemm_core256(const u16* __restrict__ A,
                                             const u16* __restrict__ Bt,
                                             u16* pool,
                                             int m0, int n0, int wm, int wn,
                                             int tid, int lo, int quad,
                                             f32x4 (&acc)[4][4]) {
    constexpr int NT = KDIM / 64;          // 16 K-tiles
    static_assert(NT >= 4 && (NT % 2) == 0, "NT even, >=4");

    // per-thread running global pointers (advance 64 elems per staged tile)
    const u16* ga[2];
    const u16* gb[4];
#pragma unroll
    for (int c = 0; c < 2; c++) {
        int chunk = c * 512 + tid, row = chunk >> 3, p = chunk & 7;
        ga[c] = A + (size_t)(m0 + row) * KDIM + (p ^ (row & 7)) * 8;
    }
#pragma unroll
    for (int c = 0; c < 4; c++) {
        int chunk = c * 512 + tid, row = chunk >> 3, p = chunk & 7;
        gb[c] = Bt + (size_t)(n0 + row) * KDIM + (p ^ (row & 7)) * 8;
    }

    auto stage = [&](int b) {   // 6 gl2lds per wave -> vmcnt +6
        u16* As = pool + b * 24576;
        u16* Bs = As + 8192;
#pragma unroll
        for (int c = 0; c < 2; c++) {
            gl2lds16(ga[c], As + (size_t)(c * 512 + tid) * 8);
            ga[c] += 64;
        }
#pragma unroll
        for (int c = 0; c < 4; c++) {
            gl2lds16(gb[c], Bs + (size_t)(c * 512 + tid) * 8);
            gb[c] += 64;
        }
    };

    bf16x8 afA[2][4], bwA[2][4], afB[2][4], bwB[2][4];

    auto ldfrag = [&](int b, bf16x8 (&af)[2][4], bf16x8 (&bw)[2][4]) {
        const u16* As = pool + b * 24576;
        const u16* Bs = As + 8192;
#pragma unroll
        for (int ks = 0; ks < 2; ks++) {
#pragma unroll
            for (int i = 0; i < 4; i++) {
                int r = wm + i * 16 + lo;
                af[ks][i] = *(const bf16x8*)&As[r * 64 + ((ks * 4 + quad) ^ (r & 7)) * 8];
            }
#pragma unroll
            for (int j = 0; j < 4; j++) {
                int r = wn + j * 16 + lo;
                bw[ks][j] = *(const bf16x8*)&Bs[r * 64 + ((ks * 4 + quad) ^ (r & 7)) * 8];
            }
        }
    };

    auto domfma = [&](bf16x8 (&af)[2][4], bf16x8 (&bw)[2][4]) {
        __builtin_amdgcn_sched_barrier(0);   // keep prefetch ds_reads above MFMA
        __builtin_amdgcn_s_setprio(1);
#pragma unroll
        for (int ks = 0; ks < 2; ks++)
#pragma unroll
            for (int i = 0; i < 4; i++)
#pragma unroll
                for (int j = 0; j < 4; j++)
                    acc[i][j] = __builtin_amdgcn_mfma_f32_16x16x32_bf16(
                        af[ks][i], bw[ks][j], acc[i][j], 0, 0, 0);
        __builtin_amdgcn_s_setprio(0);
    };

    // prologue: fill 3 buffers; read tile-0 fragments into set A
    stage(0); stage(1); stage(2);            // 18 loads in flight
    asm volatile("s_waitcnt vmcnt(12)" ::: "memory");  // my tile-0 loads landed
    __builtin_amdgcn_s_barrier();            // everyone's tile 0 in LDS
    ldfrag(0, afA, bwA);

#pragma unroll
    for (int kt = 0; kt < NT; kt++) {
        if (kt < NT - 1) {
            asm volatile("s_waitcnt lgkmcnt(0)" ::: "memory");   // frags(kt) done
            if (kt < NT - 2)
                asm volatile("s_waitcnt vmcnt(6)" ::: "memory"); // tile kt+1 landed
            else
                asm volatile("s_waitcnt vmcnt(0)" ::: "memory"); // last tile landed
            __builtin_amdgcn_s_barrier();    // collective free + visible
            if (kt + 3 < NT) stage(kt % 3);  // tile kt+3 into freed buffer
            if (kt & 1) ldfrag((kt + 1) % 3, afA, bwA);
            else        ldfrag((kt + 1) % 3, afB, bwB);
        }
        if (kt & 1) domfma(afB, bwB);
        else        domfma(afA, bwA);
    }
}

// GEMM1: qkv = Xb @ Wqkv_t^T + b.  Q scattered to [bh][t][d] PRE-SCALED by
// (1/sqrt(dk))*log2(e); K to [bh][t][d]; V TRANSPOSED to [bh][d][t].
__global__ __launch_bounds__(512, 1) void gemm1_mfma(const u16* __restrict__ A,
                                                     const u16* __restrict__ Bt,
                                                     const float* __restrict__ bias,
                                                     u16* __restrict__ qkv) {
    __shared__ u16 pool[3 * 24576];          // 144 KB
    const int tid = threadIdx.x;
    const int lane = tid & 63, wv = tid >> 6;
    const int lo = lane & 15, quad = lane >> 4;
    // bijective XCD-chunked swizzle: nwg = 768 = 8 * 96
    const int gx = 12;
    int lin = blockIdx.y * gx + blockIdx.x;
    int swz = (lin & 7) * 96 + (lin >> 3);
    const int n0 = (swz % gx) * 256;
    const int m0 = (swz / gx) * 128;
    const int wm = (wv >> 2) * 64, wn = (wv & 3) * 64;   // 2M x 4N waves
    const float scale2 = 0.18033688011112042f;  // (1/8) * log2(e)
    f32x4 acc[4][4] = {};

    gemm_core256<1024>(A, Bt, pool, m0, n0, wm, wn, tid, lo, quad, acc);

    const int whichw = (n0 + wn) >> 10;   // uniform per wave (0=Q,1=K,2=V)
    if (whichw == 2) {
        // V plane: [bh][d][t], pack 4 consecutive t (C-layout rows) per store
#pragma unroll
        for (int i = 0; i < 4; i++) {
            int mb = m0 + wm + i * 16 + quad * 4;
            int b = mb >> 11, t = mb & 2047;
#pragma unroll
            for (int j = 0; j < 4; j++) {
                int n = n0 + wn + j * 16 + lo;
                int rem = n & 1023;
                int h = rem >> 6, d = rem & 63;
                float bn = bias[n];
                ushort4 o;
                o.x = f2bf(acc[i][j][0] + bn);
                o.y = f2bf(acc[i][j][1] + bn);
                o.z = f2bf(acc[i][j][2] + bn);
                o.w = f2bf(acc[i][j][3] + bn);
                *(ushort4*)&qkv[2 * PHT +
                                (((size_t)(b * HEADS + h) * DK + d) * TSEQ + t)] = o;
            }
        }
    } else {
        const float sc = (whichw == 0) ? scale2 : 1.0f;
#pragma unroll
        for (int i = 0; i < 4; i++) {
#pragma unroll
            for (int r = 0; r < 4; r++) {
                int m = m0 + wm + i * 16 + quad * 4 + r;
                int b = m >> 11, t = m & 2047;
#pragma unroll
                for (int j = 0; j < 4; j++) {
                    int n = n0 + wn + j * 16 + lo;
                    float v = (acc[i][j][r] + bias[n]) * sc;
                    int rem = n & 1023;
                    int h = rem >> 6, d = rem & 63;
                    qkv[(size_t)whichw * PHT +
                        (((size_t)(b * HEADS + h) * TSEQ + t) * DK + d)] = f2bf(v);
                }
            }
        }
    }
}

// GEMM2: out = AO @ Wo_t^T + b (fp32 out). Grid (4, 64) = 256 blocks = 1 round.
__global__ __launch_bounds__(512, 1) void gemm2_mfma(const u16* __restrict__ A,
                                                     const u16* __restrict__ Bt,
                                                     const float* __restrict__ bias,
                                                     float* __restrict__ out) {
    __shared__ u16 pool[3 * 24576];
    const int tid = threadIdx.x;
    const int lane = tid & 63, wv = tid >> 6;
    const int lo = lane & 15, quad = lane >> 4;
    // bijective XCD-chunked swizzle: nwg = 256 = 8 * 32
    int lin = blockIdx.y * 4 + blockIdx.x;
    int swz = (lin & 7) * 32 + (lin >> 3);
    const int n0 = (swz & 3) * 256;
    const int m0 = (swz >> 2) * 128;
    const int wm = (wv >> 2) * 64, wn = (wv & 3) * 64;
    f32x4 acc[4][4] = {};

    gemm_core256<1024>(A, Bt, pool, m0, n0, wm, wn, tid, lo, quad, acc);

#pragma unroll
    for (int i = 0; i < 4; i++) {
#pragma unroll
        for (int r = 0; r < 4; r++) {
            int m = m0 + wm + i * 16 + quad * 4 + r;
#pragma unroll
            for (int j = 0; j < 4; j++) {
                int n = n0 + wn + j * 16 + lo;
                out[(size_t)m * EMB + n] = acc[i][j][r] + bias[n];
            }
        }
    }
}

// ---------------------------------------------------------------------------
// MFMA flash attention v6: 32x32x16 MFMA + fully in-register P (T12).
// Swapped QK^T (mfma(K,Q)) -> lane (c=lane&31, hf=lane>>5) holds 16 P values
// of q-row c. PA fragments built in-register with cvt_pk + permlane32_swap.
// VERIFIED SEMANTICS (from m214 recipe): v_permlane32_swap_b32 D, S swaps
// D's UPPER 32 lanes with S's LOWER 32 lanes:
//   D'[i]=D[i], D'[i+32]=S[i], S'[i]=D[i+32], S'[i+32]=S[i+32]  (i<32)
// So swap(D=w0,S=w2): w0' = word0 for BOTH halves, w2' = word2. (R4 bug:
// operands were reversed -> scrambled P -> absmax 11.25.)
// No P LDS round-trip, no Q LDS staging (Q B-frags read direct from global).
// LDS 64KB: K[2] | V[2] double-buffered, same per-kt barrier + prefetch.
// Diag iteration: wave wv skips fully-masked key-tiles j > wv.
// Q (pre-scaled), K: [bh][t][d].  V: [bh][d][t].  Out: [B][T][H][64] bf16.
// ---------------------------------------------------------------------------
__global__ __launch_bounds__(256, 2) void attn_mfma(const u16* __restrict__ Qg,
                                                    const u16* __restrict__ Kg,
                                                    const u16* __restrict__ Vg,
                                                    u16* __restrict__ AO) {
    __shared__ u16 pool[4 * 8192];   // K[2] 32KB | V[2] 32KB

    const int tid = threadIdx.x;
    const int lane = tid & 63, wv = tid >> 6;
    const int c = lane & 31, hf = lane >> 5;
    const int pair = blockIdx.x, bh = blockIdx.y;
    const size_t base = (size_t)bh * TSEQ * DK;
    const int b = bh >> 4, h = bh & 15;
    const bf16x8 onesf = {0x3F80, 0x3F80, 0x3F80, 0x3F80,
                          0x3F80, 0x3F80, 0x3F80, 0x3F80};

    // stage K(kt2) and V^T(kt2) into buffer bufsel
    auto stageKV = [&](int kt2, int bufsel) {
        u16* Kd = pool + bufsel * 8192;
        u16* Vd = pool + 2 * 8192 + bufsel * 8192;
#pragma unroll
        for (int cc = 0; cc < 4; cc++) {
            int chunk = cc * 256 + tid;
            int row = chunk >> 3, p = chunk & 7;
            int pg = p ^ (row & 7);
            gl2lds16(Kg + base + (size_t)(kt2 * 128 + row) * DK + pg * 8,
                     Kd + chunk * 8);
        }
#pragma unroll
        for (int cc = 0; cc < 4; cc++) {
            int chunk = cc * 256 + tid;
            int row = chunk >> 4, p = chunk & 15;
            int pg = p ^ (row & 15);
            gl2lds16(Vg + base + (size_t)row * TSEQ + kt2 * 128 + pg * 8,
                     Vd + chunk * 8);
        }
    };

    for (int qi = 0; qi < 2; qi++) {
        const int qt = qi ? (15 - pair) : pair;
        const int q0 = qt * 128;

        __syncthreads();  // prior tile's K/V readers done
        stageKV(0, 0);
        // Q B-fragments direct from global (kt-invariant):
        // lane (c,hf) holds Q[qrow = q0+wv*32+c][dk = s*16 + hf*8 + e]
        bf16x8 bq[4];
#pragma unroll
        for (int s = 0; s < 4; s++)
            bq[s] = *(const bf16x8*)&Qg[base + (size_t)(q0 + wv * 32 + c) * DK +
                                        s * 16 + hf * 8];
        __syncthreads();  // K0/V0 ready (drains vmcnt: Q regs also landed)

        f32x16 O0 = {}, O1 = {}, ls = {};

        for (int kt = 0; kt <= qt; kt++) {
            const int cur = kt & 1;
            if (kt) __syncthreads();          // all waves done kt-1; prefetch(kt) landed
            if (kt < qt) stageKV(kt + 1, cur ^ 1);   // flies across kt's compute
            const u16* Ksc = pool + cur * 8192;
            const u16* Vtc = pool + 2 * 8192 + cur * 8192;
            const bool diag = (kt == qt);

#pragma unroll
            for (int j = 0; j < 4; j++) {
                if (!(diag && j > wv)) {      // skip fully-masked tiles on diag
                    // QK^T for 32-key tile j: st = S^T[key][qrow=c]
                    f32x16 st = {};
#pragma unroll
                    for (int s = 0; s < 4; s++) {
                        int row = j * 32 + c;
                        bf16x8 ak = *(const bf16x8*)&Ksc[row * 64 +
                                        (((s << 1) + hf) ^ (row & 7)) * 8];
                        st = __builtin_amdgcn_mfma_f32_32x32x16_bf16(
                            ak, bq[s], st, 0, 0, 0);
                    }
                    // P = exp2(S) (no max); mask only the partial tile j==wv
                    const bool part = diag && (j == wv);
#pragma unroll
                    for (int r = 0; r < 16; r++) {
                        float e = __builtin_amdgcn_exp2f(st[r]);
                        if (part) {
                            int ko = (r & 3) + 8 * (r >> 2) + 4 * hf;  // key in tile
                            if (ko > c) e = 0.f;                       // key > qrow
                        }
                        st[r] = e;
                    }
                    // PV: 2 k-steps of 16 keys; PA built in-register
#pragma unroll
                    for (int ks = 0; ks < 2; ks++) {
                        const int br = ks * 8;
                        unsigned int w0 = pk2bf(st[br + 0], st[br + 1]);
                        unsigned int w1 = pk2bf(st[br + 2], st[br + 3]);
                        unsigned int w2 = pk2bf(st[br + 4], st[br + 5]);
                        unsigned int w3 = pk2bf(st[br + 6], st[br + 7]);
                        // swap(D=w0,S=w2): w0'<-word0 (both halves), w2'<-word2
                        asm volatile("v_permlane32_swap_b32 %0, %1"
                                     : "+v"(w0), "+v"(w2));
                        asm volatile("v_permlane32_swap_b32 %0, %1"
                                     : "+v"(w1), "+v"(w3));
                        union { u32x4 w; bf16x8 v; } pu;
                        pu.w[0] = w0; pu.w[1] = w1; pu.w[2] = w2; pu.w[3] = w3;
                        // V B-fragments: lane (c,hf) reads V^T[d][8 keys]
                        const int p0 = j * 4 + ks * 2 + hf;
                        bf16x8 bv0 = *(const bf16x8*)&Vtc[c * 128 +
                                        (p0 ^ (c & 15)) * 8];
                        bf16x8 bv1 = *(const bf16x8*)&Vtc[(32 + c) * 128 +
                                        (p0 ^ (c & 15)) * 8];
                        O0 = __builtin_amdgcn_mfma_f32_32x32x16_bf16(
                            pu.v, bv0, O0, 0, 0, 0);
                        O1 = __builtin_amdgcn_mfma_f32_32x32x16_bf16(
                            pu.v, bv1, O1, 0, 0, 0);
                        ls = __builtin_amdgcn_mfma_f32_32x32x16_bf16(
                            pu.v, onesf, ls, 0, 0, 0);
                    }
                }
            }
        }

        // epilogue: normalize by l, store [B][T][H][DK] bf16
#pragma unroll
        for (int r = 0; r < 16; r++) {
            int qrow = q0 + wv * 32 + (r & 3) + 8 * (r >> 2) + 4 * hf;
            float inv = 1.f / ls[r];
            size_t o = (((size_t)b * TSEQ + qrow) * HEADS + h) * DK;
            AO[o + c]      = f2bf(O0[r] * inv);
            AO[o + 32 + c] = f2bf(O1[r] * inv);
        }
    }
}

// ---------------------------------------------------------------------------
extern "C" void kernel_launch(void* const* d_in, const int* in_sizes, int n_in,
                              void* d_out, int out_size, void* d_ws, size_t ws_size,
                              hipStream_t stream) {
    const float* x    = (const float*)d_in[0];
    const float* Wqkv = (const float*)d_in[1];
    const float* bqkv = (const float*)d_in[2];
    const float* Wo   = (const float*)d_in[3];
    const float* bo   = (const float*)d_in[4];
    float* out = (float*)d_out;

    // workspace layout (u16 elems): [Xb 8.4M | Wt 3.1M | Wot 1M | QKV 25.2M]
    u16* Xb  = (u16*)d_ws;
    u16* Wt  = Xb + PHT;                    // [3072][1024]
    u16* Wot = Wt + (size_t)NQKV * EMB;     // [1024][1024]
    u16* qkv = Wot + (size_t)EMB * EMB;     // Q,K: [bh][t][d]; V: [bh][d][t]
    u16* AO  = Xb;                          // overlay: Xb dead after gemm1

    convert_x<<<MROWS * EMB / 1024, 256, 0, stream>>>(x, Xb);
    transpose_both<<<dim3(96 + 32, 32), 256, 0, stream>>>(Wqkv, Wo, Wt, Wot);

    gemm1_mfma<<<dim3(NQKV / 256, MROWS / 128), 512, 0, stream>>>(Xb, Wt, bqkv, qkv);
    attn_mfma<<<dim3(8, BATCH * HEADS), 256, 0, stream>>>(
        qkv, qkv + PHT, qkv + 2 * PHT, AO);
    gemm2_mfma<<<dim3(EMB / 256, MROWS / 128), 512, 0, stream>>>(AO, Wot, bo, out);
}

// Round 6
// 239.117 us; speedup vs baseline: 1.0211x; 1.0211x over previous
//
#include <hip/hip_runtime.h>
#include <hip/hip_bf16.h>
#include <math.h>

typedef unsigned short u16;
typedef __attribute__((ext_vector_type(8))) short bf16x8;
typedef __attribute__((ext_vector_type(4))) float f32x4;
typedef __attribute__((ext_vector_type(16))) float f32x16;
typedef __attribute__((ext_vector_type(4))) unsigned int u32x4;

#define BATCH 4
#define TSEQ  2048
#define HEADS 16
#define DK    64
#define EMB   1024
#define MROWS 8192            // B*T
#define NQKV  3072
#define PHT   ((size_t)MROWS * EMB)   // 8388608 elems per Q/K/V plane

__device__ __forceinline__ u16 f2bf(float f) {
    union { float f; unsigned int i; } v;
    v.f = f;
    unsigned int x = v.i;
    return (u16)((x + 0x7FFFu + ((x >> 16) & 1u)) >> 16);  // RNE
}

// packed 2xfp32 -> 2xbf16 (RNE) in one u32
__device__ __forceinline__ unsigned int pk2bf(float a, float b) {
    float2 f2; f2.x = a; f2.y = b;
    union { __hip_bfloat162 h; unsigned int u; } cv;
    cv.h = __float22bfloat162_rn(f2);
    return cv.u;
}

// async 16B global->LDS (dest = wave-uniform base + lane*16)
__device__ __forceinline__ void gl2lds16(const u16* g, u16* l) {
    __builtin_amdgcn_global_load_lds(
        (const __attribute__((address_space(1))) unsigned int*)g,
        (__attribute__((address_space(3))) unsigned int*)l, 16, 0, 0);
}

// ---------------------------------------------------------------------------
// prep: fp32 -> bf16 convert (X); both weight transposes in ONE launch
// ---------------------------------------------------------------------------
__global__ __launch_bounds__(256) void convert_x(const float* __restrict__ X,
                                                 u16* __restrict__ Xb) {
    int i = (blockIdx.x * 256 + threadIdx.x) * 4;
    float4 v = *(const float4*)&X[i];
    ushort4 o;
    o.x = f2bf(v.x); o.y = f2bf(v.y); o.z = f2bf(v.z); o.w = f2bf(v.w);
    *(ushort4*)&Xb[i] = o;
}

// bx < 96 -> Wqkv (N=3072); else Wo (N=1024). K=1024 for both.
__global__ __launch_bounds__(256) void transpose_both(const float* __restrict__ Wqkv,
                                                      const float* __restrict__ Wo,
                                                      u16* __restrict__ Wt,
                                                      u16* __restrict__ Wot) {
    __shared__ float tile[32][33];
    const int tx = threadIdx.x & 31, ty = threadIdx.x >> 5;  // 32 x 8
    const int K = 1024;
    const float* W;
    u16* D;
    int N, bx;
    if (blockIdx.x < 96) { W = Wqkv; D = Wt; N = 3072; bx = blockIdx.x; }
    else                 { W = Wo;   D = Wot; N = 1024; bx = blockIdx.x - 96; }
    const int by = blockIdx.y;
#pragma unroll
    for (int s = 0; s < 4; s++)
        tile[ty + 8 * s][tx] = W[(size_t)(by * 32 + ty + 8 * s) * N + bx * 32 + tx];
    __syncthreads();
#pragma unroll
    for (int s = 0; s < 4; s++)
        D[(size_t)(bx * 32 + ty + 8 * s) * K + by * 32 + tx] = f2bf(tile[tx][ty + 8 * s]);
}

// ---------------------------------------------------------------------------
// MFMA GEMM core v3: 128x256 tile, BK=64, 8 waves, triple-buffered LDS +
// counted vmcnt + register-fragment double-buffer (one barrier per K-tile).
// ---------------------------------------------------------------------------
template <int KDIM>
__device__ __forceinline__ void gemm_core256(const u16* __restrict__ A,
                                             const u16* __restrict__ Bt,
                                             u16* pool,
                                             int m0, int n0, int wm, int wn,
                                             int tid, int lo, int quad,
                                             f32x4 (&acc)[4][4]) {
    constexpr int NT = KDIM / 64;          // 16 K-tiles
    static_assert(NT >= 4 && (NT % 2) == 0, "NT even, >=4");

    // per-thread running global pointers (advance 64 elems per staged tile)
    const u16* ga[2];
    const u16* gb[4];
#pragma unroll
    for (int c = 0; c < 2; c++) {
        int chunk = c * 512 + tid, row = chunk >> 3, p = chunk & 7;
        ga[c] = A + (size_t)(m0 + row) * KDIM + (p ^ (row & 7)) * 8;
    }
#pragma unroll
    for (int c = 0; c < 4; c++) {
        int chunk = c * 512 + tid, row = chunk >> 3, p = chunk & 7;
        gb[c] = Bt + (size_t)(n0 + row) * KDIM + (p ^ (row & 7)) * 8;
    }

    auto stage = [&](int b) {   // 6 gl2lds per wave -> vmcnt +6
        u16* As = pool + b * 24576;
        u16* Bs = As + 8192;
#pragma unroll
        for (int c = 0; c < 2; c++) {
            gl2lds16(ga[c], As + (size_t)(c * 512 + tid) * 8);
            ga[c] += 64;
        }
#pragma unroll
        for (int c = 0; c < 4; c++) {
            gl2lds16(gb[c], Bs + (size_t)(c * 512 + tid) * 8);
            gb[c] += 64;
        }
    };

    bf16x8 afA[2][4], bwA[2][4], afB[2][4], bwB[2][4];

    auto ldfrag = [&](int b, bf16x8 (&af)[2][4], bf16x8 (&bw)[2][4]) {
        const u16* As = pool + b * 24576;
        const u16* Bs = As + 8192;
#pragma unroll
        for (int ks = 0; ks < 2; ks++) {
#pragma unroll
            for (int i = 0; i < 4; i++) {
                int r = wm + i * 16 + lo;
                af[ks][i] = *(const bf16x8*)&As[r * 64 + ((ks * 4 + quad) ^ (r & 7)) * 8];
            }
#pragma unroll
            for (int j = 0; j < 4; j++) {
                int r = wn + j * 16 + lo;
                bw[ks][j] = *(const bf16x8*)&Bs[r * 64 + ((ks * 4 + quad) ^ (r & 7)) * 8];
            }
        }
    };

    auto domfma = [&](bf16x8 (&af)[2][4], bf16x8 (&bw)[2][4]) {
        __builtin_amdgcn_sched_barrier(0);   // keep prefetch ds_reads above MFMA
        __builtin_amdgcn_s_setprio(1);
#pragma unroll
        for (int ks = 0; ks < 2; ks++)
#pragma unroll
            for (int i = 0; i < 4; i++)
#pragma unroll
                for (int j = 0; j < 4; j++)
                    acc[i][j] = __builtin_amdgcn_mfma_f32_16x16x32_bf16(
                        af[ks][i], bw[ks][j], acc[i][j], 0, 0, 0);
        __builtin_amdgcn_s_setprio(0);
    };

    // prologue: fill 3 buffers; read tile-0 fragments into set A
    stage(0); stage(1); stage(2);            // 18 loads in flight
    asm volatile("s_waitcnt vmcnt(12)" ::: "memory");  // my tile-0 loads landed
    __builtin_amdgcn_s_barrier();            // everyone's tile 0 in LDS
    ldfrag(0, afA, bwA);

#pragma unroll
    for (int kt = 0; kt < NT; kt++) {
        if (kt < NT - 1) {
            asm volatile("s_waitcnt lgkmcnt(0)" ::: "memory");   // frags(kt) done
            if (kt < NT - 2)
                asm volatile("s_waitcnt vmcnt(6)" ::: "memory"); // tile kt+1 landed
            else
                asm volatile("s_waitcnt vmcnt(0)" ::: "memory"); // last tile landed
            __builtin_amdgcn_s_barrier();    // collective free + visible
            if (kt + 3 < NT) stage(kt % 3);  // tile kt+3 into freed buffer
            if (kt & 1) ldfrag((kt + 1) % 3, afA, bwA);
            else        ldfrag((kt + 1) % 3, afB, bwB);
        }
        if (kt & 1) domfma(afB, bwB);
        else        domfma(afA, bwA);
    }
}

// GEMM1: qkv = Xb @ Wqkv_t^T + b.  Q scattered to [bh][t][d] PRE-SCALED by
// (1/sqrt(dk))*log2(e); K to [bh][t][d]; V TRANSPOSED to [bh][d][t].
__global__ __launch_bounds__(512, 1) void gemm1_mfma(const u16* __restrict__ A,
                                                     const u16* __restrict__ Bt,
                                                     const float* __restrict__ bias,
                                                     u16* __restrict__ qkv) {
    __shared__ u16 pool[3 * 24576];          // 144 KB
    const int tid = threadIdx.x;
    const int lane = tid & 63, wv = tid >> 6;
    const int lo = lane & 15, quad = lane >> 4;
    // L2-patch XCD swizzle: 768 blocks = 8 XCD x 3 patches x (8m x 4n).
    // Co-resident 32 blocks/XCD form an 8m x 4n patch: A 8x256KB + B 4x512KB
    // = 4 MB = one XCD's L2 -> panel refetch served from L2, not L3/HBM.
    // (dispatcher round-robins workgroup->XCD by linear id: xcd = lin % 8)
    int lin = blockIdx.y * 12 + blockIdx.x;
    int xcd = lin & 7, ord = lin >> 3;       // ord 0..95 sequential on this XCD
    int patch = ord >> 5, loc = ord & 31;    // 3 patches of 32 blocks
    const int m0 = (xcd * 8 + (loc >> 2)) * 128;   // 8 m-rows per XCD (A hot)
    const int n0 = (patch * 4 + (loc & 3)) * 256;  // 4 n-cols per patch
    const int wm = (wv >> 2) * 64, wn = (wv & 3) * 64;   // 2M x 4N waves
    const float scale2 = 0.18033688011112042f;  // (1/8) * log2(e)
    f32x4 acc[4][4] = {};

    gemm_core256<1024>(A, Bt, pool, m0, n0, wm, wn, tid, lo, quad, acc);

    const int whichw = (n0 + wn) >> 10;   // uniform per wave (0=Q,1=K,2=V)
    if (whichw == 2) {
        // V plane: [bh][d][t], pack 4 consecutive t (C-layout rows) per store
#pragma unroll
        for (int i = 0; i < 4; i++) {
            int mb = m0 + wm + i * 16 + quad * 4;
            int b = mb >> 11, t = mb & 2047;
#pragma unroll
            for (int j = 0; j < 4; j++) {
                int n = n0 + wn + j * 16 + lo;
                int rem = n & 1023;
                int h = rem >> 6, d = rem & 63;
                float bn = bias[n];
                ushort4 o;
                o.x = f2bf(acc[i][j][0] + bn);
                o.y = f2bf(acc[i][j][1] + bn);
                o.z = f2bf(acc[i][j][2] + bn);
                o.w = f2bf(acc[i][j][3] + bn);
                *(ushort4*)&qkv[2 * PHT +
                                (((size_t)(b * HEADS + h) * DK + d) * TSEQ + t)] = o;
            }
        }
    } else {
        const float sc = (whichw == 0) ? scale2 : 1.0f;
#pragma unroll
        for (int i = 0; i < 4; i++) {
#pragma unroll
            for (int r = 0; r < 4; r++) {
                int m = m0 + wm + i * 16 + quad * 4 + r;
                int b = m >> 11, t = m & 2047;
#pragma unroll
                for (int j = 0; j < 4; j++) {
                    int n = n0 + wn + j * 16 + lo;
                    float v = (acc[i][j][r] + bias[n]) * sc;
                    int rem = n & 1023;
                    int h = rem >> 6, d = rem & 63;
                    qkv[(size_t)whichw * PHT +
                        (((size_t)(b * HEADS + h) * TSEQ + t) * DK + d)] = f2bf(v);
                }
            }
        }
    }
}

// GEMM2: out = AO @ Wo_t^T + b (fp32 out). 256 blocks = 8 XCD x (8m x 4n).
__global__ __launch_bounds__(512, 1) void gemm2_mfma(const u16* __restrict__ A,
                                                     const u16* __restrict__ Bt,
                                                     const float* __restrict__ bias,
                                                     float* __restrict__ out) {
    __shared__ u16 pool[3 * 24576];
    const int tid = threadIdx.x;
    const int lane = tid & 63, wv = tid >> 6;
    const int lo = lane & 15, quad = lane >> 4;
    // L2-patch XCD swizzle: 32 blocks/XCD = one 8m x 4n patch (A 2MB + B 2MB)
    int lin = blockIdx.y * 4 + blockIdx.x;
    int xcd = lin & 7, ord = lin >> 3;       // ord 0..31
    const int m0 = (xcd * 8 + (ord >> 2)) * 128;
    const int n0 = (ord & 3) * 256;
    const int wm = (wv >> 2) * 64, wn = (wv & 3) * 64;
    f32x4 acc[4][4] = {};

    gemm_core256<1024>(A, Bt, pool, m0, n0, wm, wn, tid, lo, quad, acc);

#pragma unroll
    for (int i = 0; i < 4; i++) {
#pragma unroll
        for (int r = 0; r < 4; r++) {
            int m = m0 + wm + i * 16 + quad * 4 + r;
#pragma unroll
            for (int j = 0; j < 4; j++) {
                int n = n0 + wn + j * 16 + lo;
                out[(size_t)m * EMB + n] = acc[i][j][r] + bias[n];
            }
        }
    }
}

// ---------------------------------------------------------------------------
// MFMA flash attention v6: 32x32x16 MFMA + fully in-register P (T12).
// Swapped QK^T (mfma(K,Q)) -> lane (c=lane&31, hf=lane>>5) holds 16 P values
// of q-row c. PA fragments built in-register with cvt_pk + permlane32_swap
// (swap(D=w0,S=w2): w0' = word0 for both halves, w2' = word2).
// v6.1: + s_setprio(1) around MFMA clusters (T5: +4-7% attn, m191).
// LDS 64KB: K[2] | V[2] double-buffered, per-kt barrier + prefetch.
// Q (pre-scaled), K: [bh][t][d].  V: [bh][d][t].  Out: [B][T][H][64] bf16.
// ---------------------------------------------------------------------------
__global__ __launch_bounds__(256, 2) void attn_mfma(const u16* __restrict__ Qg,
                                                    const u16* __restrict__ Kg,
                                                    const u16* __restrict__ Vg,
                                                    u16* __restrict__ AO) {
    __shared__ u16 pool[4 * 8192];   // K[2] 32KB | V[2] 32KB

    const int tid = threadIdx.x;
    const int lane = tid & 63, wv = tid >> 6;
    const int c = lane & 31, hf = lane >> 5;
    const int pair = blockIdx.x, bh = blockIdx.y;
    const size_t base = (size_t)bh * TSEQ * DK;
    const int b = bh >> 4, h = bh & 15;
    const bf16x8 onesf = {0x3F80, 0x3F80, 0x3F80, 0x3F80,
                          0x3F80, 0x3F80, 0x3F80, 0x3F80};

    // stage K(kt2) and V^T(kt2) into buffer bufsel
    auto stageKV = [&](int kt2, int bufsel) {
        u16* Kd = pool + bufsel * 8192;
        u16* Vd = pool + 2 * 8192 + bufsel * 8192;
#pragma unroll
        for (int cc = 0; cc < 4; cc++) {
            int chunk = cc * 256 + tid;
            int row = chunk >> 3, p = chunk & 7;
            int pg = p ^ (row & 7);
            gl2lds16(Kg + base + (size_t)(kt2 * 128 + row) * DK + pg * 8,
                     Kd + chunk * 8);
        }
#pragma unroll
        for (int cc = 0; cc < 4; cc++) {
            int chunk = cc * 256 + tid;
            int row = chunk >> 4, p = chunk & 15;
            int pg = p ^ (row & 15);
            gl2lds16(Vg + base + (size_t)row * TSEQ + kt2 * 128 + pg * 8,
                     Vd + chunk * 8);
        }
    };

    for (int qi = 0; qi < 2; qi++) {
        const int qt = qi ? (15 - pair) : pair;
        const int q0 = qt * 128;

        __syncthreads();  // prior tile's K/V readers done
        stageKV(0, 0);
        // Q B-fragments direct from global (kt-invariant):
        // lane (c,hf) holds Q[qrow = q0+wv*32+c][dk = s*16 + hf*8 + e]
        bf16x8 bq[4];
#pragma unroll
        for (int s = 0; s < 4; s++)
            bq[s] = *(const bf16x8*)&Qg[base + (size_t)(q0 + wv * 32 + c) * DK +
                                        s * 16 + hf * 8];
        __syncthreads();  // K0/V0 ready (drains vmcnt: Q regs also landed)

        f32x16 O0 = {}, O1 = {}, ls = {};

        for (int kt = 0; kt <= qt; kt++) {
            const int cur = kt & 1;
            if (kt) __syncthreads();          // all waves done kt-1; prefetch(kt) landed
            if (kt < qt) stageKV(kt + 1, cur ^ 1);   // flies across kt's compute
            const u16* Ksc = pool + cur * 8192;
            const u16* Vtc = pool + 2 * 8192 + cur * 8192;
            const bool diag = (kt == qt);

#pragma unroll
            for (int j = 0; j < 4; j++) {
                if (!(diag && j > wv)) {      // skip fully-masked tiles on diag
                    // QK^T for 32-key tile j: st = S^T[key][qrow=c]
                    f32x16 st = {};
                    __builtin_amdgcn_s_setprio(1);
#pragma unroll
                    for (int s = 0; s < 4; s++) {
                        int row = j * 32 + c;
                        bf16x8 ak = *(const bf16x8*)&Ksc[row * 64 +
                                        (((s << 1) + hf) ^ (row & 7)) * 8];
                        st = __builtin_amdgcn_mfma_f32_32x32x16_bf16(
                            ak, bq[s], st, 0, 0, 0);
                    }
                    __builtin_amdgcn_s_setprio(0);
                    // P = exp2(S) (no max); mask only the partial tile j==wv
                    const bool part = diag && (j == wv);
#pragma unroll
                    for (int r = 0; r < 16; r++) {
                        float e = __builtin_amdgcn_exp2f(st[r]);
                        if (part) {
                            int ko = (r & 3) + 8 * (r >> 2) + 4 * hf;  // key in tile
                            if (ko > c) e = 0.f;                       // key > qrow
                        }
                        st[r] = e;
                    }
                    // PV: 2 k-steps of 16 keys; PA built in-register
#pragma unroll
                    for (int ks = 0; ks < 2; ks++) {
                        const int br = ks * 8;
                        unsigned int w0 = pk2bf(st[br + 0], st[br + 1]);
                        unsigned int w1 = pk2bf(st[br + 2], st[br + 3]);
                        unsigned int w2 = pk2bf(st[br + 4], st[br + 5]);
                        unsigned int w3 = pk2bf(st[br + 6], st[br + 7]);
                        // swap(D=w0,S=w2): w0'<-word0 (both halves), w2'<-word2
                        asm volatile("v_permlane32_swap_b32 %0, %1"
                                     : "+v"(w0), "+v"(w2));
                        asm volatile("v_permlane32_swap_b32 %0, %1"
                                     : "+v"(w1), "+v"(w3));
                        union { u32x4 w; bf16x8 v; } pu;
                        pu.w[0] = w0; pu.w[1] = w1; pu.w[2] = w2; pu.w[3] = w3;
                        // V B-fragments: lane (c,hf) reads V^T[d][8 keys]
                        const int p0 = j * 4 + ks * 2 + hf;
                        bf16x8 bv0 = *(const bf16x8*)&Vtc[c * 128 +
                                        (p0 ^ (c & 15)) * 8];
                        bf16x8 bv1 = *(const bf16x8*)&Vtc[(32 + c) * 128 +
                                        (p0 ^ (c & 15)) * 8];
                        __builtin_amdgcn_s_setprio(1);
                        O0 = __builtin_amdgcn_mfma_f32_32x32x16_bf16(
                            pu.v, bv0, O0, 0, 0, 0);
                        O1 = __builtin_amdgcn_mfma_f32_32x32x16_bf16(
                            pu.v, bv1, O1, 0, 0, 0);
                        ls = __builtin_amdgcn_mfma_f32_32x32x16_bf16(
                            pu.v, onesf, ls, 0, 0, 0);
                        __builtin_amdgcn_s_setprio(0);
                    }
                }
            }
        }

        // epilogue: normalize by l, store [B][T][H][DK] bf16
#pragma unroll
        for (int r = 0; r < 16; r++) {
            int qrow = q0 + wv * 32 + (r & 3) + 8 * (r >> 2) + 4 * hf;
            float inv = 1.f / ls[r];
            size_t o = (((size_t)b * TSEQ + qrow) * HEADS + h) * DK;
            AO[o + c]      = f2bf(O0[r] * inv);
            AO[o + 32 + c] = f2bf(O1[r] * inv);
        }
    }
}

// ---------------------------------------------------------------------------
extern "C" void kernel_launch(void* const* d_in, const int* in_sizes, int n_in,
                              void* d_out, int out_size, void* d_ws, size_t ws_size,
                              hipStream_t stream) {
    const float* x    = (const float*)d_in[0];
    const float* Wqkv = (const float*)d_in[1];
    const float* bqkv = (const float*)d_in[2];
    const float* Wo   = (const float*)d_in[3];
    const float* bo   = (const float*)d_in[4];
    float* out = (float*)d_out;

    // workspace layout (u16 elems): [Xb 8.4M | Wt 3.1M | Wot 1M | QKV 25.2M]
    u16* Xb  = (u16*)d_ws;
    u16* Wt  = Xb + PHT;                    // [3072][1024]
    u16* Wot = Wt + (size_t)NQKV * EMB;     // [1024][1024]
    u16* qkv = Wot + (size_t)EMB * EMB;     // Q,K: [bh][t][d]; V: [bh][d][t]
    u16* AO  = Xb;                          // overlay: Xb dead after gemm1

    convert_x<<<MROWS * EMB / 1024, 256, 0, stream>>>(x, Xb);
    transpose_both<<<dim3(96 + 32, 32), 256, 0, stream>>>(Wqkv, Wo, Wt, Wot);

    gemm1_mfma<<<dim3(NQKV / 256, MROWS / 128), 512, 0, stream>>>(Xb, Wt, bqkv, qkv);
    attn_mfma<<<dim3(8, BATCH * HEADS), 256, 0, stream>>>(
        qkv, qkv + PHT, qkv + 2 * PHT, AO);
    gemm2_mfma<<<dim3(EMB / 256, MROWS / 128), 512, 0, stream>>>(AO, Wot, bo, out);
}

// Round 8
// 221.732 us; speedup vs baseline: 1.1012x; 1.0784x over previous
//
#include <hip/hip_runtime.h>
#include <hip/hip_bf16.h>
#include <math.h>

typedef unsigned short u16;
typedef __attribute__((ext_vector_type(8))) short bf16x8;
typedef __attribute__((ext_vector_type(4))) float f32x4;
typedef __attribute__((ext_vector_type(16))) float f32x16;
typedef __attribute__((ext_vector_type(4))) unsigned int u32x4;

#define BATCH 4
#define TSEQ  2048
#define HEADS 16
#define DK    64
#define EMB   1024
#define MROWS 8192            // B*T
#define NQKV  3072
#define PHT   ((size_t)MROWS * EMB)   // 8388608 elems per Q/K/V plane

__device__ __forceinline__ u16 f2bf(float f) {
    union { float f; unsigned int i; } v;
    v.f = f;
    unsigned int x = v.i;
    return (u16)((x + 0x7FFFu + ((x >> 16) & 1u)) >> 16);  // RNE
}

// packed 2xfp32 -> 2xbf16 (RNE) in one u32
__device__ __forceinline__ unsigned int pk2bf(float a, float b) {
    float2 f2; f2.x = a; f2.y = b;
    union { __hip_bfloat162 h; unsigned int u; } cv;
    cv.h = __float22bfloat162_rn(f2);
    return cv.u;
}

// async 16B global->LDS (dest = wave-uniform base + lane*16)
__device__ __forceinline__ void gl2lds16(const u16* g, u16* l) {
    __builtin_amdgcn_global_load_lds(
        (const __attribute__((address_space(1))) unsigned int*)g,
        (__attribute__((address_space(3))) unsigned int*)l, 16, 0, 0);
}

// ---------------------------------------------------------------------------
// prep: fp32 -> bf16 convert (X); both weight transposes in ONE launch
// ---------------------------------------------------------------------------
__global__ __launch_bounds__(256) void convert_x(const float* __restrict__ X,
                                                 u16* __restrict__ Xb) {
    int i = (blockIdx.x * 256 + threadIdx.x) * 4;
    float4 v = *(const float4*)&X[i];
    ushort4 o;
    o.x = f2bf(v.x); o.y = f2bf(v.y); o.z = f2bf(v.z); o.w = f2bf(v.w);
    *(ushort4*)&Xb[i] = o;
}

// bx < 96 -> Wqkv (N=3072); else Wo (N=1024). K=1024 for both.
__global__ __launch_bounds__(256) void transpose_both(const float* __restrict__ Wqkv,
                                                      const float* __restrict__ Wo,
                                                      u16* __restrict__ Wt,
                                                      u16* __restrict__ Wot) {
    __shared__ float tile[32][33];
    const int tx = threadIdx.x & 31, ty = threadIdx.x >> 5;  // 32 x 8
    const int K = 1024;
    const float* W;
    u16* D;
    int N, bx;
    if (blockIdx.x < 96) { W = Wqkv; D = Wt; N = 3072; bx = blockIdx.x; }
    else                 { W = Wo;   D = Wot; N = 1024; bx = blockIdx.x - 96; }
    const int by = blockIdx.y;
#pragma unroll
    for (int s = 0; s < 4; s++)
        tile[ty + 8 * s][tx] = W[(size_t)(by * 32 + ty + 8 * s) * N + bx * 32 + tx];
    __syncthreads();
#pragma unroll
    for (int s = 0; s < 4; s++)
        D[(size_t)(bx * 32 + ty + 8 * s) * K + by * 32 + tx] = f2bf(tile[tx][ty + 8 * s]);
}

// ---------------------------------------------------------------------------
// MFMA GEMM core v3: 128x256 tile, BK=64, 8 waves, triple-buffered LDS +
// counted vmcnt + register-fragment double-buffer (one barrier per K-tile).
// ---------------------------------------------------------------------------
template <int KDIM>
__device__ __forceinline__ void gemm_core256(const u16* __restrict__ A,
                                             const u16* __restrict__ Bt,
                                             u16* pool,
                                             int m0, int n0, int wm, int wn,
                                             int tid, int lo, int quad,
                                             f32x4 (&acc)[4][4]) {
    constexpr int NT = KDIM / 64;          // 16 K-tiles
    static_assert(NT >= 4 && (NT % 2) == 0, "NT even, >=4");

    // per-thread running global pointers (advance 64 elems per staged tile)
    const u16* ga[2];
    const u16* gb[4];
#pragma unroll
    for (int c = 0; c < 2; c++) {
        int chunk = c * 512 + tid, row = chunk >> 3, p = chunk & 7;
        ga[c] = A + (size_t)(m0 + row) * KDIM + (p ^ (row & 7)) * 8;
    }
#pragma unroll
    for (int c = 0; c < 4; c++) {
        int chunk = c * 512 + tid, row = chunk >> 3, p = chunk & 7;
        gb[c] = Bt + (size_t)(n0 + row) * KDIM + (p ^ (row & 7)) * 8;
    }

    auto stage = [&](int b) {   // 6 gl2lds per wave -> vmcnt +6
        u16* As = pool + b * 24576;
        u16* Bs = As + 8192;
#pragma unroll
        for (int c = 0; c < 2; c++) {
            gl2lds16(ga[c], As + (size_t)(c * 512 + tid) * 8);
            ga[c] += 64;
        }
#pragma unroll
        for (int c = 0; c < 4; c++) {
            gl2lds16(gb[c], Bs + (size_t)(c * 512 + tid) * 8);
            gb[c] += 64;
        }
    };

    bf16x8 afA[2][4], bwA[2][4], afB[2][4], bwB[2][4];

    auto ldfrag = [&](int b, bf16x8 (&af)[2][4], bf16x8 (&bw)[2][4]) {
        const u16* As = pool + b * 24576;
        const u16* Bs = As + 8192;
#pragma unroll
        for (int ks = 0; ks < 2; ks++) {
#pragma unroll
            for (int i = 0; i < 4; i++) {
                int r = wm + i * 16 + lo;
                af[ks][i] = *(const bf16x8*)&As[r * 64 + ((ks * 4 + quad) ^ (r & 7)) * 8];
            }
#pragma unroll
            for (int j = 0; j < 4; j++) {
                int r = wn + j * 16 + lo;
                bw[ks][j] = *(const bf16x8*)&Bs[r * 64 + ((ks * 4 + quad) ^ (r & 7)) * 8];
            }
        }
    };

    auto domfma = [&](bf16x8 (&af)[2][4], bf16x8 (&bw)[2][4]) {
        __builtin_amdgcn_sched_barrier(0);   // keep prefetch ds_reads above MFMA
        __builtin_amdgcn_s_setprio(1);
#pragma unroll
        for (int ks = 0; ks < 2; ks++)
#pragma unroll
            for (int i = 0; i < 4; i++)
#pragma unroll
                for (int j = 0; j < 4; j++)
                    acc[i][j] = __builtin_amdgcn_mfma_f32_16x16x32_bf16(
                        af[ks][i], bw[ks][j], acc[i][j], 0, 0, 0);
        __builtin_amdgcn_s_setprio(0);
    };

    // prologue: fill 3 buffers; read tile-0 fragments into set A
    stage(0); stage(1); stage(2);            // 18 loads in flight
    asm volatile("s_waitcnt vmcnt(12)" ::: "memory");  // my tile-0 loads landed
    __builtin_amdgcn_s_barrier();            // everyone's tile 0 in LDS
    ldfrag(0, afA, bwA);

#pragma unroll
    for (int kt = 0; kt < NT; kt++) {
        if (kt < NT - 1) {
            asm volatile("s_waitcnt lgkmcnt(0)" ::: "memory");   // frags(kt) done
            if (kt < NT - 2)
                asm volatile("s_waitcnt vmcnt(6)" ::: "memory"); // tile kt+1 landed
            else
                asm volatile("s_waitcnt vmcnt(0)" ::: "memory"); // last tile landed
            __builtin_amdgcn_s_barrier();    // collective free + visible
            if (kt + 3 < NT) stage(kt % 3);  // tile kt+3 into freed buffer
            if (kt & 1) ldfrag((kt + 1) % 3, afA, bwA);
            else        ldfrag((kt + 1) % 3, afB, bwB);
        }
        if (kt & 1) domfma(afB, bwB);
        else        domfma(afA, bwA);
    }
}

// GEMM1: qkv = Xb @ Wqkv_t^T + b.  Q scattered to [bh][t][d] PRE-SCALED by
// (1/sqrt(dk))*log2(e); K to [bh][t][d]; V TRANSPOSED to [bh][d][t].
__global__ __launch_bounds__(512, 1) void gemm1_mfma(const u16* __restrict__ A,
                                                     const u16* __restrict__ Bt,
                                                     const float* __restrict__ bias,
                                                     u16* __restrict__ qkv) {
    __shared__ u16 pool[3 * 24576];          // 144 KB
    const int tid = threadIdx.x;
    const int lane = tid & 63, wv = tid >> 6;
    const int lo = lane & 15, quad = lane >> 4;
    // L2-patch XCD swizzle: 768 blocks = 8 XCD x 3 patches x (8m x 4n).
    // Co-resident 32 blocks/XCD form an 8m x 4n patch: A 8x256KB + B 4x512KB
    // = 4 MB = one XCD's L2 -> panel refetch served from L2, not L3/HBM.
    // (R6 verified: gemm1 ~64 -> ~48-50 us with this mapping)
    int lin = blockIdx.y * 12 + blockIdx.x;
    int xcd = lin & 7, ord = lin >> 3;       // ord 0..95 sequential on this XCD
    int patch = ord >> 5, loc = ord & 31;    // 3 patches of 32 blocks
    const int m0 = (xcd * 8 + (loc >> 2)) * 128;   // 8 m-rows per XCD (A hot)
    const int n0 = (patch * 4 + (loc & 3)) * 256;  // 4 n-cols per patch
    const int wm = (wv >> 2) * 64, wn = (wv & 3) * 64;   // 2M x 4N waves
    const float scale2 = 0.18033688011112042f;  // (1/8) * log2(e)
    f32x4 acc[4][4] = {};

    gemm_core256<1024>(A, Bt, pool, m0, n0, wm, wn, tid, lo, quad, acc);

    const int whichw = (n0 + wn) >> 10;   // uniform per wave (0=Q,1=K,2=V)
    if (whichw == 2) {
        // V plane: [bh][d][t], pack 4 consecutive t (C-layout rows) per store
#pragma unroll
        for (int i = 0; i < 4; i++) {
            int mb = m0 + wm + i * 16 + quad * 4;
            int b = mb >> 11, t = mb & 2047;
#pragma unroll
            for (int j = 0; j < 4; j++) {
                int n = n0 + wn + j * 16 + lo;
                int rem = n & 1023;
                int h = rem >> 6, d = rem & 63;
                float bn = bias[n];
                ushort4 o;
                o.x = f2bf(acc[i][j][0] + bn);
                o.y = f2bf(acc[i][j][1] + bn);
                o.z = f2bf(acc[i][j][2] + bn);
                o.w = f2bf(acc[i][j][3] + bn);
                *(ushort4*)&qkv[2 * PHT +
                                (((size_t)(b * HEADS + h) * DK + d) * TSEQ + t)] = o;
            }
        }
    } else {
        const float sc = (whichw == 0) ? scale2 : 1.0f;
#pragma unroll
        for (int i = 0; i < 4; i++) {
#pragma unroll
            for (int r = 0; r < 4; r++) {
                int m = m0 + wm + i * 16 + quad * 4 + r;
                int b = m >> 11, t = m & 2047;
#pragma unroll
                for (int j = 0; j < 4; j++) {
                    int n = n0 + wn + j * 16 + lo;
                    float v = (acc[i][j][r] + bias[n]) * sc;
                    int rem = n & 1023;
                    int h = rem >> 6, d = rem & 63;
                    qkv[(size_t)whichw * PHT +
                        (((size_t)(b * HEADS + h) * TSEQ + t) * DK + d)] = f2bf(v);
                }
            }
        }
    }
}

// GEMM2: out = AO @ Wo_t^T + b (fp32 out). 256 blocks = 8 XCD x (8m x 4n).
__global__ __launch_bounds__(512, 1) void gemm2_mfma(const u16* __restrict__ A,
                                                     const u16* __restrict__ Bt,
                                                     const float* __restrict__ bias,
                                                     float* __restrict__ out) {
    __shared__ u16 pool[3 * 24576];
    const int tid = threadIdx.x;
    const int lane = tid & 63, wv = tid >> 6;
    const int lo = lane & 15, quad = lane >> 4;
    // L2-patch XCD swizzle: 32 blocks/XCD = one 8m x 4n patch (A 2MB + B 2MB)
    int lin = blockIdx.y * 4 + blockIdx.x;
    int xcd = lin & 7, ord = lin >> 3;       // ord 0..31
    const int m0 = (xcd * 8 + (ord >> 2)) * 128;
    const int n0 = (ord & 3) * 256;
    const int wm = (wv >> 2) * 64, wn = (wv & 3) * 64;
    f32x4 acc[4][4] = {};

    gemm_core256<1024>(A, Bt, pool, m0, n0, wm, wn, tid, lo, quad, acc);

#pragma unroll
    for (int i = 0; i < 4; i++) {
#pragma unroll
        for (int r = 0; r < 4; r++) {
            int m = m0 + wm + i * 16 + quad * 4 + r;
#pragma unroll
            for (int j = 0; j < 4; j++) {
                int n = n0 + wn + j * 16 + lo;
                out[(size_t)m * EMB + n] = acc[i][j][r] + bias[n];
            }
        }
    }
}

// ---------------------------------------------------------------------------
// MFMA flash attention v7: 32x32x16 MFMA + fully in-register P (T12).
// Swapped QK^T (mfma(K,Q)) -> lane (c=lane&31, hf=lane>>5) holds 16 P values
// of q-row c. PA fragments built in-register with cvt_pk + permlane32_swap
// (swap(D=w0,S=w2): w0' = word0 for both halves, w2' = word2).
// v7: setprio REMOVED (R6: -13us; barrier-synced waves have no role split —
// m190 case, not m191). Grid is (bh=64, pair=8) so lin%8 = bh%8: all 8
// pair-blocks sharing one bh's K/V land on ONE XCD; 8 bh x 512KB = 4MB = L2.
// (R6 counter: FETCH_SIZE 146.5MB ~= 3x unique data -> cross-XCD re-fetch.)
// LDS 64KB: K[2] | V[2] double-buffered, per-kt barrier + prefetch.
// Q (pre-scaled), K: [bh][t][d].  V: [bh][d][t].  Out: [B][T][H][64] bf16.
// ---------------------------------------------------------------------------
__global__ __launch_bounds__(256, 2) void attn_mfma(const u16* __restrict__ Qg,
                                                    const u16* __restrict__ Kg,
                                                    const u16* __restrict__ Vg,
                                                    u16* __restrict__ AO) {
    __shared__ u16 pool[4 * 8192];   // K[2] 32KB | V[2] 32KB

    const int tid = threadIdx.x;
    const int lane = tid & 63, wv = tid >> 6;
    const int c = lane & 31, hf = lane >> 5;
    const int pair = blockIdx.y, bh = blockIdx.x;   // v7: swapped for XCD locality
    const size_t base = (size_t)bh * TSEQ * DK;
    const int b = bh >> 4, h = bh & 15;
    const bf16x8 onesf = {0x3F80, 0x3F80, 0x3F80, 0x3F80,
                          0x3F80, 0x3F80, 0x3F80, 0x3F80};

    // stage K(kt2) and V^T(kt2) into buffer bufsel
    auto stageKV = [&](int kt2, int bufsel) {
        u16* Kd = pool + bufsel * 8192;
        u16* Vd = pool + 2 * 8192 + bufsel * 8192;
#pragma unroll
        for (int cc = 0; cc < 4; cc++) {
            int chunk = cc * 256 + tid;
            int row = chunk >> 3, p = chunk & 7;
            int pg = p ^ (row & 7);
            gl2lds16(Kg + base + (size_t)(kt2 * 128 + row) * DK + pg * 8,
                     Kd + chunk * 8);
        }
#pragma unroll
        for (int cc = 0; cc < 4; cc++) {
            int chunk = cc * 256 + tid;
            int row = chunk >> 4, p = chunk & 15;
            int pg = p ^ (row & 15);
            gl2lds16(Vg + base + (size_t)row * TSEQ + kt2 * 128 + pg * 8,
                     Vd + chunk * 8);
        }
    };

    for (int qi = 0; qi < 2; qi++) {
        const int qt = qi ? (15 - pair) : pair;
        const int q0 = qt * 128;

        __syncthreads();  // prior tile's K/V readers done
        stageKV(0, 0);
        // Q B-fragments direct from global (kt-invariant):
        // lane (c,hf) holds Q[qrow = q0+wv*32+c][dk = s*16 + hf*8 + e]
        bf16x8 bq[4];
#pragma unroll
        for (int s = 0; s < 4; s++)
            bq[s] = *(const bf16x8*)&Qg[base + (size_t)(q0 + wv * 32 + c) * DK +
                                        s * 16 + hf * 8];
        __syncthreads();  // K0/V0 ready (drains vmcnt: Q regs also landed)

        f32x16 O0 = {}, O1 = {}, ls = {};

        for (int kt = 0; kt <= qt; kt++) {
            const int cur = kt & 1;
            if (kt) __syncthreads();          // all waves done kt-1; prefetch(kt) landed
            if (kt < qt) stageKV(kt + 1, cur ^ 1);   // flies across kt's compute
            const u16* Ksc = pool + cur * 8192;
            const u16* Vtc = pool + 2 * 8192 + cur * 8192;
            const bool diag = (kt == qt);

#pragma unroll
            for (int j = 0; j < 4; j++) {
                if (!(diag && j > wv)) {      // skip fully-masked tiles on diag
                    // QK^T for 32-key tile j: st = S^T[key][qrow=c]
                    f32x16 st = {};
#pragma unroll
                    for (int s = 0; s < 4; s++) {
                        int row = j * 32 + c;
                        bf16x8 ak = *(const bf16x8*)&Ksc[row * 64 +
                                        (((s << 1) + hf) ^ (row & 7)) * 8];
                        st = __builtin_amdgcn_mfma_f32_32x32x16_bf16(
                            ak, bq[s], st, 0, 0, 0);
                    }
                    // P = exp2(S) (no max); mask only the partial tile j==wv
                    const bool part = diag && (j == wv);
#pragma unroll
                    for (int r = 0; r < 16; r++) {
                        float e = __builtin_amdgcn_exp2f(st[r]);
                        if (part) {
                            int ko = (r & 3) + 8 * (r >> 2) + 4 * hf;  // key in tile
                            if (ko > c) e = 0.f;                       // key > qrow
                        }
                        st[r] = e;
                    }
                    // PV: 2 k-steps of 16 keys; PA built in-register
#pragma unroll
                    for (int ks = 0; ks < 2; ks++) {
                        const int br = ks * 8;
                        unsigned int w0 = pk2bf(st[br + 0], st[br + 1]);
                        unsigned int w1 = pk2bf(st[br + 2], st[br + 3]);
                        unsigned int w2 = pk2bf(st[br + 4], st[br + 5]);
                        unsigned int w3 = pk2bf(st[br + 6], st[br + 7]);
                        // swap(D=w0,S=w2): w0'<-word0 (both halves), w2'<-word2
                        asm volatile("v_permlane32_swap_b32 %0, %1"
                                     : "+v"(w0), "+v"(w2));
                        asm volatile("v_permlane32_swap_b32 %0, %1"
                                     : "+v"(w1), "+v"(w3));
                        union { u32x4 w; bf16x8 v; } pu;
                        pu.w[0] = w0; pu.w[1] = w1; pu.w[2] = w2; pu.w[3] = w3;
                        // V B-fragments: lane (c,hf) reads V^T[d][8 keys]
                        const int p0 = j * 4 + ks * 2 + hf;
                        bf16x8 bv0 = *(const bf16x8*)&Vtc[c * 128 +
                                        (p0 ^ (c & 15)) * 8];
                        bf16x8 bv1 = *(const bf16x8*)&Vtc[(32 + c) * 128 +
                                        (p0 ^ (c & 15)) * 8];
                        O0 = __builtin_amdgcn_mfma_f32_32x32x16_bf16(
                            pu.v, bv0, O0, 0, 0, 0);
                        O1 = __builtin_amdgcn_mfma_f32_32x32x16_bf16(
                            pu.v, bv1, O1, 0, 0, 0);
                        ls = __builtin_amdgcn_mfma_f32_32x32x16_bf16(
                            pu.v, onesf, ls, 0, 0, 0);
                    }
                }
            }
        }

        // epilogue: normalize by l, store [B][T][H][DK] bf16
#pragma unroll
        for (int r = 0; r < 16; r++) {
            int qrow = q0 + wv * 32 + (r & 3) + 8 * (r >> 2) + 4 * hf;
            float inv = 1.f / ls[r];
            size_t o = (((size_t)b * TSEQ + qrow) * HEADS + h) * DK;
            AO[o + c]      = f2bf(O0[r] * inv);
            AO[o + 32 + c] = f2bf(O1[r] * inv);
        }
    }
}

// ---------------------------------------------------------------------------
extern "C" void kernel_launch(void* const* d_in, const int* in_sizes, int n_in,
                              void* d_out, int out_size, void* d_ws, size_t ws_size,
                              hipStream_t stream) {
    const float* x    = (const float*)d_in[0];
    const float* Wqkv = (const float*)d_in[1];
    const float* bqkv = (const float*)d_in[2];
    const float* Wo   = (const float*)d_in[3];
    const float* bo   = (const float*)d_in[4];
    float* out = (float*)d_out;

    // workspace layout (u16 elems): [Xb 8.4M | Wt 3.1M | Wot 1M | QKV 25.2M]
    u16* Xb  = (u16*)d_ws;
    u16* Wt  = Xb + PHT;                    // [3072][1024]
    u16* Wot = Wt + (size_t)NQKV * EMB;     // [1024][1024]
    u16* qkv = Wot + (size_t)EMB * EMB;     // Q,K: [bh][t][d]; V: [bh][d][t]
    u16* AO  = Xb;                          // overlay: Xb dead after gemm1

    convert_x<<<MROWS * EMB / 1024, 256, 0, stream>>>(x, Xb);
    transpose_both<<<dim3(96 + 32, 32), 256, 0, stream>>>(Wqkv, Wo, Wt, Wot);

    gemm1_mfma<<<dim3(NQKV / 256, MROWS / 128), 512, 0, stream>>>(Xb, Wt, bqkv, qkv);
    attn_mfma<<<dim3(BATCH * HEADS, 8), 256, 0, stream>>>(
        qkv, qkv + PHT, qkv + 2 * PHT, AO);
    gemm2_mfma<<<dim3(EMB / 256, MROWS / 128), 512, 0, stream>>>(AO, Wot, bo, out);
}